// Round 6
// baseline (267.375 us; speedup 1.0000x reference)
//
#include <hip/hip_runtime.h>
#include <hip/hip_bf16.h>

typedef unsigned short u16;
typedef short bf16x8 __attribute__((ext_vector_type(8)));
typedef float f32x4 __attribute__((ext_vector_type(4)));

// 2^x via raw v_exp_f32 (NOT __exp2f: glibc math.h declares a host __exp2f,
// which collides in hipcc's merged TU)
#define EXP2(x) __builtin_amdgcn_exp2f(x)

static __device__ __forceinline__ u16 f2bf(float f) {
  union { float f; unsigned u; } a; a.f = f;
  unsigned r = a.u + 0x7fffu + ((a.u >> 16) & 1u);  // RNE
  return (u16)(r >> 16);
}

static __device__ __forceinline__ unsigned pkbf(float a, float b) {
  union { __hip_bfloat162 h; unsigned u; } c;
  c.h = __float22bfloat162_rn(make_float2(a, b));
  return c.u;  // low 16 = a, high 16 = b
}

static __device__ __forceinline__ bf16x8 as_bf(int4 v) {
  union { int4 i; bf16x8 b; } u; u.i = v; return u.b;
}

// async global->LDS, 16B per lane; LDS dest = wave-uniform base + lane*16
#define GLDS16(g, l)                                         \
  __builtin_amdgcn_global_load_lds(                          \
      (const __attribute__((address_space(1))) void*)(g),    \
      (__attribute__((address_space(3))) void*)(l), 16, 0, 0)

// ---------------- fused prep: x cast + 4 weight transposes ----------------
__global__ __launch_bounds__(256) void prep(
    const float* __restrict__ x, u16* __restrict__ Xb,
    const float* __restrict__ Wq, u16* __restrict__ Wqt,
    const float* __restrict__ Wk, u16* __restrict__ Wkt,
    const float* __restrict__ Wv, u16* __restrict__ Wvt,
    const float* __restrict__ Wu, u16* __restrict__ Wut) {
  const int bid = blockIdx.x, tid = threadIdx.x;
  if (bid < 1024) {
    int i = bid * 256 + tid;
    const float4* p = (const float4*)x + (size_t)i * 2;
    float4 a = p[0], b = p[1];
    union { unsigned s[4]; int4 v; } u2;
    u2.s[0] = pkbf(a.x, a.y); u2.s[1] = pkbf(a.z, a.w);
    u2.s[2] = pkbf(b.x, b.y); u2.s[3] = pkbf(b.z, b.w);
    ((int4*)Xb)[i] = u2.v;
    return;
  }
  const int which = (bid - 1024) >> 6;
  const float* in; u16* out; int R, C;
  if (which == 0)      { in = Wq; out = Wqt; R = 256;  C = 2048; }
  else if (which == 1) { in = Wk; out = Wkt; R = 256;  C = 2048; }
  else if (which == 2) { in = Wv; out = Wvt; R = 256;  C = 2048; }
  else                 { in = Wu; out = Wut; R = 2048; C = 256;  }
  int T = ((bid - 1024) & 63) * 256 + tid;
  int c = T % C;
  int r0 = (T / C) * 32;
  __align__(16) u16 tmp[32];
#pragma unroll
  for (int j = 0; j < 32; ++j) tmp[j] = f2bf(in[(size_t)(r0 + j) * C + c]);
#pragma unroll
  for (int q = 0; q < 4; ++q)
    *(int4*)(out + (size_t)c * R + r0 + q * 8) = *(int4*)&tmp[q * 8];
}

// ---------------- fused QKV GEMM (M=8192,N=2048,K=256, 128x128 tiles) ----------
__global__ __launch_bounds__(256) void gemm_qkv(const u16* __restrict__ A,
                                                const u16* __restrict__ Wt,
                                                const float* __restrict__ bq,
                                                const float* __restrict__ bk,
                                                const float* __restrict__ bv,
                                                u16* __restrict__ Qw,
                                                u16* __restrict__ Kw,
                                                u16* __restrict__ Vt) {
  constexpr int BM = 128, BN = 128, BK = 64;
  __shared__ int4 smem4[2048];  // 32 KB: As(16K) | Bs(16K); reused for transpose
  int4* As4 = smem4;
  int4* Bs4 = smem4 + 1024;
  const int tid = threadIdx.x;
  const int w = tid >> 6, lane = tid & 63, lq = lane & 15, quad = lane >> 4;
  const int wm = w >> 1, wn = w & 1;
  const int m0 = blockIdx.y * BM, n0 = blockIdx.x * BN;
  const int z = blockIdx.z;

  const u16* Btz = Wt + (size_t)z * 2048 * 256;
  const float* bias = (z == 0) ? bq : (z == 1 ? bk : bv);

  const int srow = lane >> 3;
  const int scb = (lane & 7) ^ ((lane >> 3) & 7);

  f32x4 acc[4][4];
#pragma unroll
  for (int mi = 0; mi < 4; ++mi)
#pragma unroll
    for (int ni = 0; ni < 4; ++ni) {
      f32x4 z4 = {0.f, 0.f, 0.f, 0.f};
      acc[mi][ni] = z4;
    }

  for (int k0 = 0; k0 < 256; k0 += BK) {
    __syncthreads();
#pragma unroll
    for (int it = 0; it < 4; ++it) {
      int r = (w * 4 + it) * 8 + srow;
      GLDS16(A + (size_t)(m0 + r) * 256 + k0 + scb * 8,
             (char*)As4 + (w * 4 + it) * 1024);
    }
#pragma unroll
    for (int it = 0; it < 4; ++it) {
      int r = (w * 4 + it) * 8 + srow;
      GLDS16(Btz + (size_t)(n0 + r) * 256 + k0 + scb * 8,
             (char*)Bs4 + (w * 4 + it) * 1024);
    }
    __syncthreads();
#pragma unroll
    for (int kk = 0; kk < 2; ++kk) {
      int4 af[4], bf[4];
#pragma unroll
      for (int mi = 0; mi < 4; ++mi) {
        int r = wm * 64 + mi * 16 + lq;
        af[mi] = As4[r * 8 + ((kk * 4 + quad) ^ (lq & 7))];
      }
#pragma unroll
      for (int ni = 0; ni < 4; ++ni) {
        int r = wn * 64 + ni * 16 + lq;
        bf[ni] = Bs4[r * 8 + ((kk * 4 + quad) ^ (lq & 7))];
      }
#pragma unroll
      for (int mi = 0; mi < 4; ++mi)
#pragma unroll
        for (int ni = 0; ni < 4; ++ni)
          acc[mi][ni] = __builtin_amdgcn_mfma_f32_16x16x32_bf16(
              as_bf(af[mi]), as_bf(bf[ni]), acc[mi][ni], 0, 0, 0);
    }
  }

  if (z < 2) {
    u16* Cout = z ? Kw : Qw;
#pragma unroll
    for (int mi = 0; mi < 4; ++mi)
#pragma unroll
      for (int ni = 0; ni < 4; ++ni)
#pragma unroll
        for (int r = 0; r < 4; ++r) {
          int row = m0 + wm * 64 + mi * 16 + quad * 4 + r;
          int col = n0 + wn * 64 + ni * 16 + lq;
          Cout[(size_t)row * 2048 + col] = f2bf(acc[mi][ni][r] + bias[col]);
        }
  } else {
    // V^T epilogue: transpose the 128x128 tile through LDS, store coalesced.
    __syncthreads();  // all waves done with As4/Bs4
    u16* Ts = (u16*)smem4;
#pragma unroll
    for (int mi = 0; mi < 4; ++mi)
#pragma unroll
      for (int ni = 0; ni < 4; ++ni) {
        int c = wn * 64 + ni * 16 + lq;
        int r0 = wm * 64 + mi * 16 + quad * 4;
        float vb = bias[n0 + c];
        uint2 dd;
        dd.x = pkbf(acc[mi][ni][0] + vb, acc[mi][ni][1] + vb);
        dd.y = pkbf(acc[mi][ni][2] + vb, acc[mi][ni][3] + vb);
        *(uint2*)&Ts[c * 128 + (((r0 >> 3) ^ (c & 15)) << 3) + (r0 & 7)] = dd;
      }
    __syncthreads();
    const int b = m0 >> 10, t0 = m0 & 1023;
    const int e0 = n0 & 255, h = n0 >> 8;
    const int bh = b * 8 + h;
    const int i4 = tid & 15;
#pragma unroll
    for (int cc = 0; cc < 8; ++cc) {
      int c = (tid >> 4) + cc * 16;
      int4 val = *(const int4*)&Ts[c * 128 + ((i4 ^ (c & 15)) << 3)];
      *(int4*)(Vt + (size_t)(bh * 256 + e0 + c) * 1024 + t0 + i4 * 8) = val;
    }
  }
}

// ---------------- generic GEMM (out-projection): fp32 out + bias ----------------
template <int BM, int BN>
__global__ __launch_bounds__(256) void gemm_bt(const u16* __restrict__ A,
                                               const u16* __restrict__ Bt,
                                               const float* __restrict__ bias,
                                               float* __restrict__ Cout,
                                               int M, int N, int K) {
  constexpr int BK = 64;
  constexpr int TM = BM / 2 / 16, TN = BN / 2 / 16;
  constexpr int nA = BM / 32, nB = BN / 32;
  __shared__ int4 As4[BM * 8];
  __shared__ int4 Bs4[BN * 8];
  const int tid = threadIdx.x;
  const int w = tid >> 6, lane = tid & 63, lq = lane & 15, quad = lane >> 4;
  const int wm = w >> 1, wn = w & 1;
  const int m0 = blockIdx.y * BM, n0 = blockIdx.x * BN;

  const int srow = lane >> 3;
  const int scb = (lane & 7) ^ ((lane >> 3) & 7);

  f32x4 acc[TM][TN];
#pragma unroll
  for (int mi = 0; mi < TM; ++mi)
#pragma unroll
    for (int ni = 0; ni < TN; ++ni) {
      f32x4 z4 = {0.f, 0.f, 0.f, 0.f};
      acc[mi][ni] = z4;
    }

  for (int k0 = 0; k0 < K; k0 += BK) {
    __syncthreads();
#pragma unroll
    for (int it = 0; it < nA; ++it) {
      int r = (w * nA + it) * 8 + srow;
      GLDS16(A + (size_t)(m0 + r) * K + k0 + scb * 8,
             (char*)As4 + (w * nA + it) * 1024);
    }
#pragma unroll
    for (int it = 0; it < nB; ++it) {
      int r = (w * nB + it) * 8 + srow;
      GLDS16(Bt + (size_t)(n0 + r) * K + k0 + scb * 8,
             (char*)Bs4 + (w * nB + it) * 1024);
    }
    __syncthreads();
#pragma unroll
    for (int kk = 0; kk < BK / 32; ++kk) {
      int4 af[TM], bf[TN];
#pragma unroll
      for (int mi = 0; mi < TM; ++mi) {
        int r = wm * (BM / 2) + mi * 16 + lq;
        af[mi] = As4[r * 8 + ((kk * 4 + quad) ^ (lq & 7))];
      }
#pragma unroll
      for (int ni = 0; ni < TN; ++ni) {
        int r = wn * (BN / 2) + ni * 16 + lq;
        bf[ni] = Bs4[r * 8 + ((kk * 4 + quad) ^ (lq & 7))];
      }
#pragma unroll
      for (int mi = 0; mi < TM; ++mi)
#pragma unroll
        for (int ni = 0; ni < TN; ++ni)
          acc[mi][ni] = __builtin_amdgcn_mfma_f32_16x16x32_bf16(
              as_bf(af[mi]), as_bf(bf[ni]), acc[mi][ni], 0, 0, 0);
    }
  }

#pragma unroll
  for (int mi = 0; mi < TM; ++mi)
#pragma unroll
    for (int ni = 0; ni < TN; ++ni)
#pragma unroll
      for (int r = 0; r < 4; ++r) {
        int row = m0 + wm * (BM / 2) + mi * 16 + quad * 4 + r;
        int col = n0 + wn * (BN / 2) + ni * 16 + lq;
        Cout[(size_t)row * N + col] = acc[mi][ni][r] + bias[col];
      }
}

// ---------------- flash attention, strictly causal, S^T form ----------------
// Block = 128 queries (4 waves x 32 queries, two 16-q groups per wave): each
// K/V fragment ds_read feeds TWO MFMAs -> halves LDS bytes per FLOP (the R5
// bottleneck). grid (64 bh, 8 qt) with y->qt map {7,6,5,4,0,1,2,3}: under
// round-robin dispatch each CU gets heavy+light = 18 iters uniform.
// LDS: K 32K + V^T 32K + Ps 16K = 80 KB -> 2 blocks/CU. VGPR capped at 256.
__global__ __launch_bounds__(256, 2) void attn_kernel(const u16* __restrict__ Q,
                                                      const u16* __restrict__ Km,
                                                      const u16* __restrict__ Vt,
                                                      u16* __restrict__ O) {
  const int bh = blockIdx.x;
  const int y = blockIdx.y;
  const int qt = (y < 4) ? (7 - y) : (y - 4);  // heavy first + pairing by CU
  const int b = bh >> 3, h = bh & 7;
  const int tid = threadIdx.x;
  const int w = tid >> 6, lane = tid & 63, lq = lane & 15, quad = lane >> 4;

  __shared__ int4 Ks4[2048];   // 64 key-rows x 32 int4 (256 dims), swizzled
  __shared__ int4 Vs4[2048];   // 256 e-rows  x  8 int4 (64 keys), swizzled
  __shared__ u16 Ps[8192];     // per-wave 32x64 P round-trip (4 KB/wave)
  u16* myPs = Ps + w * 2048;

  const u16* kbase = Km + (size_t)b * 2097152 + h * 256;
  const u16* vbase = Vt + (size_t)bh * 262144;

  const float SCL = 0.09016844f;  // (1/16) * log2(e): softmax in exp2 domain
  const float NEG = -3.0e38f;

  const int q0 = qt * 128 + w * 32;  // wave's first query
  const int qg[2] = {q0 + lq, q0 + 16 + lq};

  // Q B-fragments for both 16-query groups (held all kernel)
  int4 qf[2][8];
#pragma unroll
  for (int g = 0; g < 2; ++g) {
    const u16* qptr =
        Q + (size_t)(b * 1024 + q0 + g * 16 + lq) * 2048 + h * 256 + quad * 8;
#pragma unroll
    for (int kk = 0; kk < 8; ++kk) qf[g][kk] = *(const int4*)(qptr + kk * 32);
  }

  f32x4 of[2][16];
#pragma unroll
  for (int g = 0; g < 2; ++g)
#pragma unroll
    for (int i = 0; i < 16; ++i) {
      f32x4 z = {0.f, 0.f, 0.f, 0.f};
      of[g][i] = z;
    }
  float mst[2] = {NEG, NEG}, lst[2] = {0.f, 0.f};

  const int niter = 2 * qt + 2;
#pragma unroll 1
  for (int kt = 0; kt < niter; ++kt) {
    __syncthreads();  // prior iter's LDS reads complete
    {
      const u16* kb = kbase + (size_t)kt * 131072;
      const u16* vb = vbase + kt * 64;
      const int kg = (lane & 31) >> 3;
#pragma unroll
      for (int it = 0; it < 8; ++it) {
        int r = w * 16 + it * 2 + (lane >> 5);
        int p = (lane & 7) ^ (r & 7);
        GLDS16(kb + r * 2048 + (kg * 8 + p) * 8, (char*)Ks4 + (w * 8 + it) * 1024);
      }
#pragma unroll
      for (int it = 0; it < 8; ++it) {
        int rv = w * 64 + it * 8 + (lane >> 3);
        int cb = (lane & 7) ^ (rv & 7);
        GLDS16(vb + rv * 1024 + cb * 8, (char*)Vs4 + (w * 8 + it) * 1024);
      }
    }
    __syncthreads();  // staged tiles visible

    // ---- S^T = K Q^T : each kf read feeds both query groups ----
    f32x4 sc[2][4];
#pragma unroll
    for (int ns = 0; ns < 4; ++ns) {
      f32x4 a0 = {0.f, 0.f, 0.f, 0.f}, a1 = {0.f, 0.f, 0.f, 0.f};
      int r = ns * 16 + lq;
#pragma unroll
      for (int kk = 0; kk < 8; ++kk) {
        int G = kk * 4 + quad;
        int4 kf = Ks4[r * 32 + (G >> 3) * 8 + ((G & 7) ^ (lq & 7))];
        a0 = __builtin_amdgcn_mfma_f32_16x16x32_bf16(as_bf(kf), as_bf(qf[0][kk]),
                                                     a0, 0, 0, 0);
        a1 = __builtin_amdgcn_mfma_f32_16x16x32_bf16(as_bf(kf), as_bf(qf[1][kk]),
                                                     a1, 0, 0, 0);
      }
      sc[0][ns] = a0;
      sc[1][ns] = a1;
    }
    // scale (exp2 domain) + strictly-causal mask (finite NEG)
#pragma unroll
    for (int g = 0; g < 2; ++g)
#pragma unroll
      for (int ns = 0; ns < 4; ++ns) {
        int keyb = kt * 64 + ns * 16 + quad * 4;
#pragma unroll
        for (int r = 0; r < 4; ++r) {
          float v = sc[g][ns][r] * SCL;
          sc[g][ns][r] = (keyb + r >= qg[g]) ? NEG : v;
        }
      }
    // online softmax per group (lane = query, reduce across quad groups)
    float m16[2];
#pragma unroll
    for (int g = 0; g < 2; ++g) {
      float m = sc[g][0][0];
#pragma unroll
      for (int ns = 0; ns < 4; ++ns)
#pragma unroll
        for (int r = 0; r < 4; ++r) m = fmaxf(m, sc[g][ns][r]);
      m = fmaxf(m, __shfl_xor(m, 16));
      m = fmaxf(m, __shfl_xor(m, 32));
      m16[g] = m;
    }
    if (__any(m16[0] > mst[0] || m16[1] > mst[1])) {
#pragma unroll
      for (int g = 0; g < 2; ++g) {
        float mn = fmaxf(mst[g], m16[g]);
        float alpha = EXP2(mst[g] - mn);
        mst[g] = mn;
        lst[g] *= alpha;
#pragma unroll
        for (int i = 0; i < 16; ++i)
#pragma unroll
          for (int r = 0; r < 4; ++r) of[g][i][r] *= alpha;
      }
    }
#pragma unroll
    for (int g = 0; g < 2; ++g) {
      float s = 0.f;
#pragma unroll
      for (int ns = 0; ns < 4; ++ns)
#pragma unroll
        for (int r = 0; r < 4; ++r) {
          float p = EXP2(sc[g][ns][r] - mst[g]);
          sc[g][ns][r] = p;
          s += p;
        }
      s += __shfl_xor(s, 16);
      s += __shfl_xor(s, 32);
      lst[g] += s;
    }

    // ---- P^T C-layout -> B-layout via per-wave LDS (no barrier) ----
#pragma unroll
    for (int g = 0; g < 2; ++g)
#pragma unroll
      for (int ns = 0; ns < 4; ++ns) {
        int kb2 = ns * 2 + (quad >> 1);
        int base = g * 1024 + lq * 64 + ((kb2 ^ (lq & 7)) << 3) + (quad & 1) * 4;
        uint2 dd;
        dd.x = pkbf(sc[g][ns][0], sc[g][ns][1]);
        dd.y = pkbf(sc[g][ns][2], sc[g][ns][3]);
        *(uint2*)&myPs[base] = dd;
      }
    int4 pf[2][2];
#pragma unroll
    for (int g = 0; g < 2; ++g)
#pragma unroll
      for (int kk2 = 0; kk2 < 2; ++kk2) {
        int kbp = (kk2 * 4 + quad) ^ (lq & 7);
        pf[g][kk2] = *(const int4*)&myPs[g * 1024 + lq * 64 + kbp * 8];
      }
    // ---- O^T += V^T P^T : each vf read feeds both query groups ----
#pragma unroll
    for (int ns2 = 0; ns2 < 16; ++ns2) {
      int r = ns2 * 16 + lq;
#pragma unroll
      for (int kk2 = 0; kk2 < 2; ++kk2) {
        int4 vf = Vs4[r * 8 + ((kk2 * 4 + quad) ^ (lq & 7))];
        of[0][ns2] = __builtin_amdgcn_mfma_f32_16x16x32_bf16(
            as_bf(vf), as_bf(pf[0][kk2]), of[0][ns2], 0, 0, 0);
        of[1][ns2] = __builtin_amdgcn_mfma_f32_16x16x32_bf16(
            as_bf(vf), as_bf(pf[1][kk2]), of[1][ns2], 0, 0, 0);
      }
    }
  }

#pragma unroll
  for (int g = 0; g < 2; ++g) {
    float inv = lst[g] > 0.f ? 1.f / lst[g] : 0.f;
    if (qg[g] == 0) inv = 0.f;  // fully-masked first query -> zero row
    u16* optr = O + (size_t)(b * 1024 + qg[g]) * 2048 + h * 256 + quad * 4;
#pragma unroll
    for (int ns2 = 0; ns2 < 16; ++ns2) {
      uint2 o4;
      o4.x = pkbf(of[g][ns2][0] * inv, of[g][ns2][1] * inv);
      o4.y = pkbf(of[g][ns2][2] * inv, of[g][ns2][3] * inv);
      *(uint2*)(optr + ns2 * 16) = o4;
    }
  }
}

// ---------------- workspace layout (bytes) ----------------
#define WS_XB 0
#define WS_WQT 4194304   /* Wqt|Wkt|Wvt contiguous, 1 MB each */
#define WS_WUT 7340032
#define WS_QW 8388608    /* 32 MB */
#define WS_KW 41943040   /* 32 MB */
#define WS_OW 75497472   /* 32 MB */
#define WS_VTW 109051904 /* 32 MB */

extern "C" void kernel_launch(void* const* d_in, const int* in_sizes, int n_in,
                              void* d_out, int out_size, void* d_ws, size_t ws_size,
                              hipStream_t stream) {
  const float* x = (const float*)d_in[0];
  const float* Wq = (const float*)d_in[1];
  const float* bq = (const float*)d_in[2];
  const float* Wk = (const float*)d_in[3];
  const float* bk = (const float*)d_in[4];
  const float* Wv = (const float*)d_in[5];
  const float* bv = (const float*)d_in[6];
  const float* Wu = (const float*)d_in[7];
  const float* bu = (const float*)d_in[8];
  float* out = (float*)d_out;

  char* ws = (char*)d_ws;
  u16* Xb = (u16*)(ws + WS_XB);
  u16* Wqt = (u16*)(ws + WS_WQT);
  u16* Wkt = Wqt + 524288;
  u16* Wvt = Wqt + 1048576;
  u16* Wut = (u16*)(ws + WS_WUT);
  u16* Qw = (u16*)(ws + WS_QW);
  u16* Kw = (u16*)(ws + WS_KW);
  u16* Ow = (u16*)(ws + WS_OW);
  u16* Vtw = (u16*)(ws + WS_VTW);

  // 1) fused prep: x cast + all weight transposes (one dispatch)
  prep<<<1280, 256, 0, stream>>>(x, Xb, Wq, Wqt, Wk, Wkt, Wv, Wvt, Wu, Wut);

  // 2) fused QKV projections; z==2 writes V^T directly (no transpose_v pass)
  gemm_qkv<<<dim3(16, 64, 3), 256, 0, stream>>>(Xb, Wqt, bq, bk, bv, Qw, Kw, Vtw);

  // 3) causal flash attention (128-query blocks, 32 queries/wave)
  attn_kernel<<<dim3(64, 8), 256, 0, stream>>>(Qw, Kw, Vtw, Ow);

  // 4) output projection (fp32 out, fused bias) — 256 blocks = 1/CU
  gemm_bt<128, 64><<<dim3(4, 64), 256, 0, stream>>>(Ow, Wut, bu, out, 8192, 256, 2048);
}

// Round 7
// 247.524 us; speedup vs baseline: 1.0802x; 1.0802x over previous
//
#include <hip/hip_runtime.h>
#include <hip/hip_bf16.h>

typedef unsigned short u16;
typedef short bf16x8 __attribute__((ext_vector_type(8)));
typedef float f32x4 __attribute__((ext_vector_type(4)));

// 2^x via raw v_exp_f32 (NOT __exp2f: glibc math.h declares a host __exp2f,
// which collides in hipcc's merged TU)
#define EXP2(x) __builtin_amdgcn_exp2f(x)

static __device__ __forceinline__ u16 f2bf(float f) {
  union { float f; unsigned u; } a; a.f = f;
  unsigned r = a.u + 0x7fffu + ((a.u >> 16) & 1u);  // RNE
  return (u16)(r >> 16);
}

static __device__ __forceinline__ unsigned pkbf(float a, float b) {
  union { __hip_bfloat162 h; unsigned u; } c;
  c.h = __float22bfloat162_rn(make_float2(a, b));
  return c.u;  // low 16 = a, high 16 = b
}

static __device__ __forceinline__ bf16x8 as_bf(int4 v) {
  union { int4 i; bf16x8 b; } u; u.i = v; return u.b;
}

// async global->LDS, 16B per lane; LDS dest = wave-uniform base + lane*16
#define GLDS16(g, l)                                         \
  __builtin_amdgcn_global_load_lds(                          \
      (const __attribute__((address_space(1))) void*)(g),    \
      (__attribute__((address_space(3))) void*)(l), 16, 0, 0)

// ---------------- fused prep: x cast + 4 weight transposes ----------------
__global__ __launch_bounds__(256) void prep(
    const float* __restrict__ x, u16* __restrict__ Xb,
    const float* __restrict__ Wq, u16* __restrict__ Wqt,
    const float* __restrict__ Wk, u16* __restrict__ Wkt,
    const float* __restrict__ Wv, u16* __restrict__ Wvt,
    const float* __restrict__ Wu, u16* __restrict__ Wut) {
  const int bid = blockIdx.x, tid = threadIdx.x;
  if (bid < 1024) {
    int i = bid * 256 + tid;
    const float4* p = (const float4*)x + (size_t)i * 2;
    float4 a = p[0], b = p[1];
    union { unsigned s[4]; int4 v; } u2;
    u2.s[0] = pkbf(a.x, a.y); u2.s[1] = pkbf(a.z, a.w);
    u2.s[2] = pkbf(b.x, b.y); u2.s[3] = pkbf(b.z, b.w);
    ((int4*)Xb)[i] = u2.v;
    return;
  }
  const int which = (bid - 1024) >> 6;
  const float* in; u16* out; int R, C;
  if (which == 0)      { in = Wq; out = Wqt; R = 256;  C = 2048; }
  else if (which == 1) { in = Wk; out = Wkt; R = 256;  C = 2048; }
  else if (which == 2) { in = Wv; out = Wvt; R = 256;  C = 2048; }
  else                 { in = Wu; out = Wut; R = 2048; C = 256;  }
  int T = ((bid - 1024) & 63) * 256 + tid;
  int c = T % C;
  int r0 = (T / C) * 32;
  __align__(16) u16 tmp[32];
#pragma unroll
  for (int j = 0; j < 32; ++j) tmp[j] = f2bf(in[(size_t)(r0 + j) * C + c]);
#pragma unroll
  for (int q = 0; q < 4; ++q)
    *(int4*)(out + (size_t)c * R + r0 + q * 8) = *(int4*)&tmp[q * 8];
}

// ---------------- fused QKV GEMM (M=8192,N=2048,K=256, 128x128 tiles) ----------
__global__ __launch_bounds__(256) void gemm_qkv(const u16* __restrict__ A,
                                                const u16* __restrict__ Wt,
                                                const float* __restrict__ bq,
                                                const float* __restrict__ bk,
                                                const float* __restrict__ bv,
                                                u16* __restrict__ Qw,
                                                u16* __restrict__ Kw,
                                                u16* __restrict__ Vt) {
  constexpr int BM = 128, BN = 128, BK = 64;
  __shared__ int4 smem4[2048];  // 32 KB: As(16K) | Bs(16K); reused for transpose
  int4* As4 = smem4;
  int4* Bs4 = smem4 + 1024;
  const int tid = threadIdx.x;
  const int w = tid >> 6, lane = tid & 63, lq = lane & 15, quad = lane >> 4;
  const int wm = w >> 1, wn = w & 1;
  const int m0 = blockIdx.y * BM, n0 = blockIdx.x * BN;
  const int z = blockIdx.z;

  const u16* Btz = Wt + (size_t)z * 2048 * 256;
  const float* bias = (z == 0) ? bq : (z == 1 ? bk : bv);

  const int srow = lane >> 3;
  const int scb = (lane & 7) ^ ((lane >> 3) & 7);

  f32x4 acc[4][4];
#pragma unroll
  for (int mi = 0; mi < 4; ++mi)
#pragma unroll
    for (int ni = 0; ni < 4; ++ni) {
      f32x4 z4 = {0.f, 0.f, 0.f, 0.f};
      acc[mi][ni] = z4;
    }

  for (int k0 = 0; k0 < 256; k0 += BK) {
    __syncthreads();
#pragma unroll
    for (int it = 0; it < 4; ++it) {
      int r = (w * 4 + it) * 8 + srow;
      GLDS16(A + (size_t)(m0 + r) * 256 + k0 + scb * 8,
             (char*)As4 + (w * 4 + it) * 1024);
    }
#pragma unroll
    for (int it = 0; it < 4; ++it) {
      int r = (w * 4 + it) * 8 + srow;
      GLDS16(Btz + (size_t)(n0 + r) * 256 + k0 + scb * 8,
             (char*)Bs4 + (w * 4 + it) * 1024);
    }
    __syncthreads();
#pragma unroll
    for (int kk = 0; kk < 2; ++kk) {
      int4 af[4], bf[4];
#pragma unroll
      for (int mi = 0; mi < 4; ++mi) {
        int r = wm * 64 + mi * 16 + lq;
        af[mi] = As4[r * 8 + ((kk * 4 + quad) ^ (lq & 7))];
      }
#pragma unroll
      for (int ni = 0; ni < 4; ++ni) {
        int r = wn * 64 + ni * 16 + lq;
        bf[ni] = Bs4[r * 8 + ((kk * 4 + quad) ^ (lq & 7))];
      }
#pragma unroll
      for (int mi = 0; mi < 4; ++mi)
#pragma unroll
        for (int ni = 0; ni < 4; ++ni)
          acc[mi][ni] = __builtin_amdgcn_mfma_f32_16x16x32_bf16(
              as_bf(af[mi]), as_bf(bf[ni]), acc[mi][ni], 0, 0, 0);
    }
  }

  if (z < 2) {
    u16* Cout = z ? Kw : Qw;
#pragma unroll
    for (int mi = 0; mi < 4; ++mi)
#pragma unroll
      for (int ni = 0; ni < 4; ++ni)
#pragma unroll
        for (int r = 0; r < 4; ++r) {
          int row = m0 + wm * 64 + mi * 16 + quad * 4 + r;
          int col = n0 + wn * 64 + ni * 16 + lq;
          Cout[(size_t)row * 2048 + col] = f2bf(acc[mi][ni][r] + bias[col]);
        }
  } else {
    // V^T epilogue: transpose the 128x128 tile through LDS, store coalesced.
    __syncthreads();  // all waves done with As4/Bs4
    u16* Ts = (u16*)smem4;
#pragma unroll
    for (int mi = 0; mi < 4; ++mi)
#pragma unroll
      for (int ni = 0; ni < 4; ++ni) {
        int c = wn * 64 + ni * 16 + lq;
        int r0 = wm * 64 + mi * 16 + quad * 4;
        float vb = bias[n0 + c];
        uint2 dd;
        dd.x = pkbf(acc[mi][ni][0] + vb, acc[mi][ni][1] + vb);
        dd.y = pkbf(acc[mi][ni][2] + vb, acc[mi][ni][3] + vb);
        *(uint2*)&Ts[c * 128 + (((r0 >> 3) ^ (c & 15)) << 3) + (r0 & 7)] = dd;
      }
    __syncthreads();
    const int b = m0 >> 10, t0 = m0 & 1023;
    const int e0 = n0 & 255, h = n0 >> 8;
    const int bh = b * 8 + h;
    const int i4 = tid & 15;
#pragma unroll
    for (int cc = 0; cc < 8; ++cc) {
      int c = (tid >> 4) + cc * 16;
      int4 val = *(const int4*)&Ts[c * 128 + ((i4 ^ (c & 15)) << 3)];
      *(int4*)(Vt + (size_t)(bh * 256 + e0 + c) * 1024 + t0 + i4 * 8) = val;
    }
  }
}

// ---------------- generic GEMM (out-projection): fp32 out + bias ----------------
template <int BM, int BN>
__global__ __launch_bounds__(256) void gemm_bt(const u16* __restrict__ A,
                                               const u16* __restrict__ Bt,
                                               const float* __restrict__ bias,
                                               float* __restrict__ Cout,
                                               int M, int N, int K) {
  constexpr int BK = 64;
  constexpr int TM = BM / 2 / 16, TN = BN / 2 / 16;
  constexpr int nA = BM / 32, nB = BN / 32;
  __shared__ int4 As4[BM * 8];
  __shared__ int4 Bs4[BN * 8];
  const int tid = threadIdx.x;
  const int w = tid >> 6, lane = tid & 63, lq = lane & 15, quad = lane >> 4;
  const int wm = w >> 1, wn = w & 1;
  const int m0 = blockIdx.y * BM, n0 = blockIdx.x * BN;

  const int srow = lane >> 3;
  const int scb = (lane & 7) ^ ((lane >> 3) & 7);

  f32x4 acc[TM][TN];
#pragma unroll
  for (int mi = 0; mi < TM; ++mi)
#pragma unroll
    for (int ni = 0; ni < TN; ++ni) {
      f32x4 z4 = {0.f, 0.f, 0.f, 0.f};
      acc[mi][ni] = z4;
    }

  for (int k0 = 0; k0 < K; k0 += BK) {
    __syncthreads();
#pragma unroll
    for (int it = 0; it < nA; ++it) {
      int r = (w * nA + it) * 8 + srow;
      GLDS16(A + (size_t)(m0 + r) * K + k0 + scb * 8,
             (char*)As4 + (w * nA + it) * 1024);
    }
#pragma unroll
    for (int it = 0; it < nB; ++it) {
      int r = (w * nB + it) * 8 + srow;
      GLDS16(Bt + (size_t)(n0 + r) * K + k0 + scb * 8,
             (char*)Bs4 + (w * nB + it) * 1024);
    }
    __syncthreads();
#pragma unroll
    for (int kk = 0; kk < BK / 32; ++kk) {
      int4 af[TM], bf[TN];
#pragma unroll
      for (int mi = 0; mi < TM; ++mi) {
        int r = wm * (BM / 2) + mi * 16 + lq;
        af[mi] = As4[r * 8 + ((kk * 4 + quad) ^ (lq & 7))];
      }
#pragma unroll
      for (int ni = 0; ni < TN; ++ni) {
        int r = wn * (BN / 2) + ni * 16 + lq;
        bf[ni] = Bs4[r * 8 + ((kk * 4 + quad) ^ (lq & 7))];
      }
#pragma unroll
      for (int mi = 0; mi < TM; ++mi)
#pragma unroll
        for (int ni = 0; ni < TN; ++ni)
          acc[mi][ni] = __builtin_amdgcn_mfma_f32_16x16x32_bf16(
              as_bf(af[mi]), as_bf(bf[ni]), acc[mi][ni], 0, 0, 0);
    }
  }

#pragma unroll
  for (int mi = 0; mi < TM; ++mi)
#pragma unroll
    for (int ni = 0; ni < TN; ++ni)
#pragma unroll
      for (int r = 0; r < 4; ++r) {
        int row = m0 + wm * (BM / 2) + mi * 16 + quad * 4 + r;
        int col = n0 + wn * (BN / 2) + ni * 16 + lq;
        Cout[(size_t)row * N + col] = acc[mi][ni][r] + bias[col];
      }
}

// ---------------- flash attention, strictly causal, S^T form ----------------
// Block = 128 queries (4 waves x 32 q, two 16-q groups/wave: each K/V ds_read
// feeds 2 MFMAs). Each block processes the q-tile PAIR {p, 7-p} -> exactly 18
// inner iterations for EVERY block (uniform regardless of block->CU mapping —
// the R6 lesson). Double-buffered K/V staging (one barrier per iter; GLDS for
// t+1 issued right after the barrier, covered by a full compute phase).
// LDS: 2 x (K 32K + V 32K) + Ps 16K = 144 KB -> 1 block/CU; no VGPR cap.
__global__ __launch_bounds__(256, 1) void attn_kernel(const u16* __restrict__ Q,
                                                      const u16* __restrict__ Km,
                                                      const u16* __restrict__ Vt,
                                                      u16* __restrict__ O) {
  const int bh = blockIdx.x;
  const int pair = blockIdx.y;  // 0..3
  const int b = bh >> 3, h = bh & 7;
  const int tid = threadIdx.x;
  const int w = tid >> 6, lane = tid & 63, lq = lane & 15, quad = lane >> 4;

  __shared__ int4 KVs[2][4096];  // [buf][ K: 0..2047 | V: 2048..4095 ]
  __shared__ u16 Ps[8192];       // per-wave 32x64 P round-trip (4 KB/wave)
  u16* myPs = Ps + w * 2048;

  const u16* kbase = Km + (size_t)b * 2097152 + h * 256;
  const u16* vbase = Vt + (size_t)bh * 262144;

  const float SCL = 0.09016844f;  // (1/16) * log2(e): softmax in exp2 domain
  const float NEG = -3.0e38f;

  // staging geometry (global-address-side swizzle), per-wave slices
  int koffb[8], voffb[8];
  {
    const int kg = (lane & 31) >> 3;
#pragma unroll
    for (int it = 0; it < 8; ++it) {
      int r = w * 16 + it * 2 + (lane >> 5);
      int p = (lane & 7) ^ (r & 7);
      koffb[it] = r * 2048 + (kg * 8 + p) * 8;
      int rv = w * 64 + it * 8 + (lane >> 3);
      int cb = (lane & 7) ^ (rv & 7);
      voffb[it] = rv * 1024 + cb * 8;
    }
  }

#pragma unroll 1
  for (int ph = 0; ph < 2; ++ph) {
    const int qt = ph ? (7 - pair) : pair;
    const int q0 = qt * 128 + w * 32;
    const int qg[2] = {q0 + lq, q0 + 16 + lq};

    int4 qf[2][8];
#pragma unroll
    for (int g = 0; g < 2; ++g) {
      const u16* qptr =
          Q + (size_t)(b * 1024 + q0 + g * 16 + lq) * 2048 + h * 256 + quad * 8;
#pragma unroll
      for (int kk = 0; kk < 8; ++kk) qf[g][kk] = *(const int4*)(qptr + kk * 32);
    }

    f32x4 of[2][16];
#pragma unroll
    for (int g = 0; g < 2; ++g)
#pragma unroll
      for (int i = 0; i < 16; ++i) {
        f32x4 z = {0.f, 0.f, 0.f, 0.f};
        of[g][i] = z;
      }
    float mst[2] = {NEG, NEG}, lst[2] = {0.f, 0.f};

    const int niter = 2 * qt + 2;

    __syncthreads();  // previous phase's buffer reads complete
    // prefetch kt=0 into buf 0
#pragma unroll
    for (int it = 0; it < 8; ++it)
      GLDS16(kbase + koffb[it], (char*)&KVs[0][0] + (w * 8 + it) * 1024);
#pragma unroll
    for (int it = 0; it < 8; ++it)
      GLDS16(vbase + voffb[it], (char*)&KVs[0][2048] + (w * 8 + it) * 1024);

#pragma unroll 1
    for (int kt = 0; kt < niter; ++kt) {
      __syncthreads();  // drains buf[kt&1] loads; all waves done with buf[1-kt&1]
      const int cur = kt & 1;
      if (kt + 1 < niter) {  // prefetch kt+1 into the other buffer
        const u16* kb = kbase + (size_t)(kt + 1) * 131072;
        const u16* vb = vbase + (kt + 1) * 64;
        char* kd = (char*)&KVs[cur ^ 1][0];
        char* vd = (char*)&KVs[cur ^ 1][2048];
#pragma unroll
        for (int it = 0; it < 8; ++it)
          GLDS16(kb + koffb[it], kd + (w * 8 + it) * 1024);
#pragma unroll
        for (int it = 0; it < 8; ++it)
          GLDS16(vb + voffb[it], vd + (w * 8 + it) * 1024);
      }
      const int4* Ks4 = &KVs[cur][0];
      const int4* Vs4 = &KVs[cur][2048];

      // ---- S^T = K Q^T : each kf read feeds both query groups ----
      f32x4 sc[2][4];
#pragma unroll
      for (int ns = 0; ns < 4; ++ns) {
        f32x4 a0 = {0.f, 0.f, 0.f, 0.f}, a1 = {0.f, 0.f, 0.f, 0.f};
        int r = ns * 16 + lq;
#pragma unroll
        for (int kk = 0; kk < 8; ++kk) {
          int G = kk * 4 + quad;
          int4 kf = Ks4[r * 32 + (G >> 3) * 8 + ((G & 7) ^ (lq & 7))];
          a0 = __builtin_amdgcn_mfma_f32_16x16x32_bf16(as_bf(kf), as_bf(qf[0][kk]),
                                                       a0, 0, 0, 0);
          a1 = __builtin_amdgcn_mfma_f32_16x16x32_bf16(as_bf(kf), as_bf(qf[1][kk]),
                                                       a1, 0, 0, 0);
        }
        sc[0][ns] = a0;
        sc[1][ns] = a1;
      }
      // scale (exp2 domain) + strictly-causal mask (finite NEG)
#pragma unroll
      for (int g = 0; g < 2; ++g)
#pragma unroll
        for (int ns = 0; ns < 4; ++ns) {
          int keyb = kt * 64 + ns * 16 + quad * 4;
#pragma unroll
          for (int r = 0; r < 4; ++r) {
            float v = sc[g][ns][r] * SCL;
            sc[g][ns][r] = (keyb + r >= qg[g]) ? NEG : v;
          }
        }
      // online softmax per group (lane = query, reduce across quad groups)
      float m16[2];
#pragma unroll
      for (int g = 0; g < 2; ++g) {
        float m = sc[g][0][0];
#pragma unroll
        for (int ns = 0; ns < 4; ++ns)
#pragma unroll
          for (int r = 0; r < 4; ++r) m = fmaxf(m, sc[g][ns][r]);
        m = fmaxf(m, __shfl_xor(m, 16));
        m = fmaxf(m, __shfl_xor(m, 32));
        m16[g] = m;
      }
      if (__any(m16[0] > mst[0] || m16[1] > mst[1])) {
#pragma unroll
        for (int g = 0; g < 2; ++g) {
          float mn = fmaxf(mst[g], m16[g]);
          float alpha = EXP2(mst[g] - mn);
          mst[g] = mn;
          lst[g] *= alpha;
#pragma unroll
          for (int i = 0; i < 16; ++i)
#pragma unroll
            for (int r = 0; r < 4; ++r) of[g][i][r] *= alpha;
        }
      }
#pragma unroll
      for (int g = 0; g < 2; ++g) {
        float s = 0.f;
#pragma unroll
        for (int ns = 0; ns < 4; ++ns)
#pragma unroll
          for (int r = 0; r < 4; ++r) {
            float p = EXP2(sc[g][ns][r] - mst[g]);
            sc[g][ns][r] = p;
            s += p;
          }
        s += __shfl_xor(s, 16);
        s += __shfl_xor(s, 32);
        lst[g] += s;
      }

      // ---- P^T C-layout -> B-layout via per-wave LDS (no barrier) ----
#pragma unroll
      for (int g = 0; g < 2; ++g)
#pragma unroll
        for (int ns = 0; ns < 4; ++ns) {
          int kb2 = ns * 2 + (quad >> 1);
          int base = g * 1024 + lq * 64 + ((kb2 ^ (lq & 7)) << 3) + (quad & 1) * 4;
          uint2 dd;
          dd.x = pkbf(sc[g][ns][0], sc[g][ns][1]);
          dd.y = pkbf(sc[g][ns][2], sc[g][ns][3]);
          *(uint2*)&myPs[base] = dd;
        }
      int4 pf[2][2];
#pragma unroll
      for (int g = 0; g < 2; ++g)
#pragma unroll
        for (int kk2 = 0; kk2 < 2; ++kk2) {
          int kbp = (kk2 * 4 + quad) ^ (lq & 7);
          pf[g][kk2] = *(const int4*)&myPs[g * 1024 + lq * 64 + kbp * 8];
        }
      // ---- O^T += V^T P^T : each vf read feeds both query groups ----
#pragma unroll
      for (int ns2 = 0; ns2 < 16; ++ns2) {
        int r = ns2 * 16 + lq;
#pragma unroll
        for (int kk2 = 0; kk2 < 2; ++kk2) {
          int4 vf = Vs4[r * 8 + ((kk2 * 4 + quad) ^ (lq & 7))];
          of[0][ns2] = __builtin_amdgcn_mfma_f32_16x16x32_bf16(
              as_bf(vf), as_bf(pf[0][kk2]), of[0][ns2], 0, 0, 0);
          of[1][ns2] = __builtin_amdgcn_mfma_f32_16x16x32_bf16(
              as_bf(vf), as_bf(pf[1][kk2]), of[1][ns2], 0, 0, 0);
        }
      }
    }

#pragma unroll
    for (int g = 0; g < 2; ++g) {
      float inv = lst[g] > 0.f ? 1.f / lst[g] : 0.f;
      if (qg[g] == 0) inv = 0.f;  // fully-masked first query -> zero row
      u16* optr = O + (size_t)(b * 1024 + qg[g]) * 2048 + h * 256 + quad * 4;
#pragma unroll
      for (int ns2 = 0; ns2 < 16; ++ns2) {
        uint2 o4;
        o4.x = pkbf(of[g][ns2][0] * inv, of[g][ns2][1] * inv);
        o4.y = pkbf(of[g][ns2][2] * inv, of[g][ns2][3] * inv);
        *(uint2*)(optr + ns2 * 16) = o4;
      }
    }
  }
}

// ---------------- workspace layout (bytes) ----------------
#define WS_XB 0
#define WS_WQT 4194304   /* Wqt|Wkt|Wvt contiguous, 1 MB each */
#define WS_WUT 7340032
#define WS_QW 8388608    /* 32 MB */
#define WS_KW 41943040   /* 32 MB */
#define WS_OW 75497472   /* 32 MB */
#define WS_VTW 109051904 /* 32 MB */

extern "C" void kernel_launch(void* const* d_in, const int* in_sizes, int n_in,
                              void* d_out, int out_size, void* d_ws, size_t ws_size,
                              hipStream_t stream) {
  const float* x = (const float*)d_in[0];
  const float* Wq = (const float*)d_in[1];
  const float* bq = (const float*)d_in[2];
  const float* Wk = (const float*)d_in[3];
  const float* bk = (const float*)d_in[4];
  const float* Wv = (const float*)d_in[5];
  const float* bv = (const float*)d_in[6];
  const float* Wu = (const float*)d_in[7];
  const float* bu = (const float*)d_in[8];
  float* out = (float*)d_out;

  char* ws = (char*)d_ws;
  u16* Xb = (u16*)(ws + WS_XB);
  u16* Wqt = (u16*)(ws + WS_WQT);
  u16* Wkt = Wqt + 524288;
  u16* Wvt = Wqt + 1048576;
  u16* Wut = (u16*)(ws + WS_WUT);
  u16* Qw = (u16*)(ws + WS_QW);
  u16* Kw = (u16*)(ws + WS_KW);
  u16* Ow = (u16*)(ws + WS_OW);
  u16* Vtw = (u16*)(ws + WS_VTW);

  // 1) fused prep: x cast + all weight transposes (one dispatch)
  prep<<<1280, 256, 0, stream>>>(x, Xb, Wq, Wqt, Wk, Wkt, Wv, Wvt, Wu, Wut);

  // 2) fused QKV projections; z==2 writes V^T directly (no transpose_v pass)
  gemm_qkv<<<dim3(16, 64, 3), 256, 0, stream>>>(Xb, Wqt, bq, bk, bv, Qw, Kw, Vtw);

  // 3) causal flash attention (uniform 18-iter pair-blocks, double-buffered)
  attn_kernel<<<dim3(64, 4), 256, 0, stream>>>(Qw, Kw, Vtw, Ow);

  // 4) output projection (fp32 out, fused bias) — 256 blocks = 1/CU
  gemm_bt<128, 64><<<dim3(4, 64), 256, 0, stream>>>(Ow, Wut, bu, out, 8192, 256, 2048);
}